// Round 1
// 1031.500 us; speedup vs baseline: 1.0036x; 1.0036x over previous
//
#include <hip/hip_runtime.h>
#include <hip/hip_bf16.h>
#include <cstdint>

#define B_   2
#define S_   2048
#define HID_ 3072
#define H_   16
#define KV_  8
#define D_   256
#define HD_  4096   // H_*D_
#define KVD_ 2048   // KV_*D_

constexpr float EPS_   = 1e-6f;
constexpr float SCALE_ = 0.0625f;   // 256^-0.5

typedef unsigned short u16;
typedef __attribute__((ext_vector_type(8))) short bf16x8;
typedef __attribute__((ext_vector_type(4))) float f32x4;

__device__ inline float bf2f(u16 u) { return __uint_as_float(((unsigned int)u) << 16); }
__device__ inline u16 f2bf(float f) {
  unsigned int x = __float_as_uint(f);
  x += 0x7fffu + ((x >> 16) & 1u);   // RNE
  return (u16)(x >> 16);
}

// async global->LDS, 16B per lane; lds base must be wave-uniform, data lands at base + lane*16
__device__ inline void gll16(const u16* g, u16* l) {
  __builtin_amdgcn_global_load_lds((const __attribute__((address_space(1))) unsigned int*)g,
                                   (__attribute__((address_space(3))) unsigned int*)l,
                                   16, 0, 0);
}

// ---------------- elementwise cast f32 -> bf16 (n4 = n/4) ----------------
__global__ void cast_f32_bf16(const float* __restrict__ in, u16* __restrict__ out, int n4) {
  int i = blockIdx.x * blockDim.x + threadIdx.x;
  if (i < n4) {
    float4 v = ((const float4*)in)[i];
    ushort4 o;
    o.x = f2bf(v.x); o.y = f2bf(v.y); o.z = f2bf(v.z); o.w = f2bf(v.w);
    ((ushort4*)out)[i] = o;
  }
}

// ------------- transpose+cast: in[K][N] f32 -> out[N][K] bf16 -------------
__global__ void transpose_cast(const float* __restrict__ in, u16* __restrict__ out, int K, int N) {
  __shared__ __align__(16) float tile[64][65];
  int n0 = blockIdx.x * 64, k0 = blockIdx.y * 64;
  int t = threadIdx.x;
  int rr = t >> 4, cc = (t & 15) * 4;
  for (int i = 0; i < 4; i++) {
    float4 v = *(const float4*)(&in[(size_t)(k0 + rr + 16 * i) * N + n0 + cc]);
    tile[rr + 16 * i][cc + 0] = v.x; tile[rr + 16 * i][cc + 1] = v.y;
    tile[rr + 16 * i][cc + 2] = v.z; tile[rr + 16 * i][cc + 3] = v.w;
  }
  __syncthreads();
  for (int i = 0; i < 4; i++) {
    int orow = rr + 16 * i;  // n index
    ushort4 o;
    o.x = f2bf(tile[cc + 0][orow]); o.y = f2bf(tile[cc + 1][orow]);
    o.z = f2bf(tile[cc + 2][orow]); o.w = f2bf(tile[cc + 3][orow]);
    *(ushort4*)(&out[(size_t)(n0 + orow) * K + k0 + cc]) = o;
  }
}

// ------- bf16 transpose: in[4096 tok][2048 n] -> out[b][2048 n][2048 s] -------
__global__ void transpose_v(const u16* __restrict__ in, u16* __restrict__ out) {
  __shared__ __align__(16) u16 tile[64][68];
  int n0 = blockIdx.x * 64, tk0 = blockIdx.y * 64;
  int b = tk0 >> 11, s0 = tk0 & (S_ - 1);
  int t = threadIdx.x;
  int rr = t >> 4, cc = (t & 15) * 4;
  for (int i = 0; i < 4; i++) {
    ushort4 v = *(const ushort4*)(&in[(size_t)(tk0 + rr + 16 * i) * KVD_ + n0 + cc]);
    tile[rr + 16 * i][cc + 0] = v.x; tile[rr + 16 * i][cc + 1] = v.y;
    tile[rr + 16 * i][cc + 2] = v.z; tile[rr + 16 * i][cc + 3] = v.w;
  }
  __syncthreads();
  for (int i = 0; i < 4; i++) {
    int orow = rr + 16 * i;  // n index
    ushort4 o;
    o.x = tile[cc + 0][orow]; o.y = tile[cc + 1][orow];
    o.z = tile[cc + 2][orow]; o.w = tile[cc + 3][orow];
    *(ushort4*)(&out[((size_t)b << 22) + (size_t)(n0 + orow) * S_ + s0 + cc]) = o;
  }
}

// --------- GEMM: C[M][N] = A[M][K] * Bt[N][K]^T, bf16 in, f32 acc ---------
// m97 structure: 128x128 tile, BK=32, global_load_lds width-16, unpadded stride-32 LDS
template <bool OUTF32>
__global__ __launch_bounds__(256) void gemm_bf16(const u16* __restrict__ A,
                                                 const u16* __restrict__ Bt,
                                                 void* __restrict__ Cv, int M, int N, int K) {
  __shared__ __align__(16) u16 As[128 * 32];
  __shared__ __align__(16) u16 Bs[128 * 32];
  int t = threadIdx.x, lane = t & 63, wave = t >> 6;
  int wm = wave >> 1, wn = wave & 1, quad = lane >> 4, l16 = lane & 15;
  int bm = blockIdx.y * 128, bn = blockIdx.x * 128;
  f32x4 acc[4][4] = {};
  int srow = wave * 16 + (lane >> 2);
  int scol = (lane & 3) * 8;
  const u16* ap0 = A  + (size_t)(bm + srow) * K + scol;
  const u16* ap1 = A  + (size_t)(bm + 64 + srow) * K + scol;
  const u16* bp0 = Bt + (size_t)(bn + srow) * K + scol;
  const u16* bp1 = Bt + (size_t)(bn + 64 + srow) * K + scol;
  u16* asb0 = &As[wave * 512];
  u16* asb1 = &As[wave * 512 + 2048];
  u16* bsb0 = &Bs[wave * 512];
  u16* bsb1 = &Bs[wave * 512 + 2048];
  for (int k0 = 0; k0 < K; k0 += 32) {
    __syncthreads();
    gll16(ap0 + k0, asb0);
    gll16(ap1 + k0, asb1);
    gll16(bp0 + k0, bsb0);
    gll16(bp1 + k0, bsb1);
    __syncthreads();
    bf16x8 af[4], bfr[4];
    for (int i = 0; i < 4; i++)
      af[i] = *(const bf16x8*)(&As[(wm * 64 + i * 16 + l16) * 32 + quad * 8]);
    for (int j = 0; j < 4; j++)
      bfr[j] = *(const bf16x8*)(&Bs[(wn * 64 + j * 16 + l16) * 32 + quad * 8]);
    for (int i = 0; i < 4; i++)
      for (int j = 0; j < 4; j++)
        acc[i][j] = __builtin_amdgcn_mfma_f32_16x16x32_bf16(af[i], bfr[j], acc[i][j], 0, 0, 0);
  }
  for (int i = 0; i < 4; i++)
    for (int j = 0; j < 4; j++)
      for (int r = 0; r < 4; r++) {
        int row = bm + wm * 64 + i * 16 + quad * 4 + r;
        int col = bn + wn * 64 + j * 16 + l16;
        float v = acc[i][j][r];
        if (OUTF32) ((float*)Cv)[(size_t)row * N + col] = v;
        else ((u16*)Cv)[(size_t)row * N + col] = f2bf(v);
      }
}

// ----- fused RMSNorm + RoPE, in place on bf16 [B*S][nh][256]; 1 wave/head -----
__global__ void rmsnorm_rope(u16* __restrict__ x, const float* __restrict__ w,
                             const float* __restrict__ fc, const float* __restrict__ fsn,
                             int nh, float outscale) {
  int token = blockIdx.x;
  int head = blockIdx.y * 4 + (threadIdx.x >> 6);
  if (head >= nh) return;
  int lane = threadIdx.x & 63;
  int s = token & (S_ - 1);
  u16* p = x + (size_t)(token * nh + head) * D_;
  float v0 = bf2f(p[lane]);
  float v1 = bf2f(p[lane + 64]);
  float v2 = bf2f(p[lane + 128]);
  float v3 = bf2f(p[lane + 192]);
  float ss = v0 * v0 + v1 * v1 + v2 * v2 + v3 * v3;
  for (int off = 32; off; off >>= 1) ss += __shfl_xor(ss, off, 64);
  float rs = rsqrtf(ss * (1.0f / D_) + EPS_);
  float n0 = v0 * rs * (1.0f + w[lane]);
  float n1 = v1 * rs * (1.0f + w[lane + 64]);
  float n2 = v2 * rs * (1.0f + w[lane + 128]);
  float n3 = v3 * rs * (1.0f + w[lane + 192]);
  float c0 = fc[s * 128 + lane], s0 = fsn[s * 128 + lane];
  float c1 = fc[s * 128 + lane + 64], s1 = fsn[s * 128 + lane + 64];
  p[lane]       = f2bf((n0 * c0 - n2 * s0) * outscale);
  p[lane + 128] = f2bf((n0 * s0 + n2 * c0) * outscale);
  p[lane + 64]  = f2bf((n1 * c1 - n3 * s1) * outscale);
  p[lane + 192] = f2bf((n1 * s1 + n3 * c1) * outscale);
}

// ---------------- flash attention, causal, GQA rep=2, D=256 ----------------
// grid (S/64, H, B) longest-first; 256 threads; wave = 16 q rows; 32-key tiles.
// v2: double-buffered K/V staging with counted vmcnt (T3 minimum 2-phase) +
//     XOR slot-swizzle on K/V/P LDS (pre-swizzled global source, T2/m173).
__global__ __launch_bounds__(256, 2) void flash_attn(const u16* __restrict__ Q,
                                                     const u16* __restrict__ Kb,
                                                     const u16* __restrict__ Vt,
                                                     u16* __restrict__ O) {
  __shared__ __align__(16) u16 Ks[2][8 * 1024];   // [buf][chunk c][key 0..31][slot-swz 32 d]
  __shared__ __align__(16) u16 Vs[2][8 * 1024];   // [buf][d 0..255][slot-swz 32 k]
  __shared__ __align__(16) u16 Ps[4][16 * 32];    // per-wave P round-trip (slot-swz)
  int t = threadIdx.x, lane = t & 63, wave = t >> 6;
  int quad = lane >> 4, l16 = lane & 15;
  int qb = ((int)gridDim.x - 1 - (int)blockIdx.x) * 64;  // longest blocks first
  int h = blockIdx.y, b = blockIdx.z;
  int kvh = h >> 1;
  int qw = qb + wave * 16;

  // Q fragments (A-layout) straight from global
  bf16x8 qf[8];
  const u16* qp = Q + ((size_t)(b * S_) + qw + l16) * HD_ + h * D_;
#pragma unroll
  for (int c = 0; c < 8; c++) qf[c] = *(const bf16x8*)(qp + c * 32 + quad * 8);

  f32x4 o_acc[16] = {};
  float m_r[4], l_r[4];
  for (int r = 0; r < 4; r++) { m_r[r] = -3e38f; l_r[r] = 0.f; }

  int nkt = (qb + 64) >> 5;
  // XOR slot swizzle: within each staged row (32 bf16 = 4 slots of 16B), the
  // 16B slot s of row k physically holds data block s ^ (k&3).  gll16 writes
  // linearly, so the *global source* is pre-swizzled per lane; reads apply the
  // same XOR -> identical data, conflict-free banks (8 words/bank, the min).
  int swz = ((lane & 3) ^ ((lane >> 2) & 3)) * 8;        // staging-side d/k offset
  int rswz = (quad ^ (l16 & 3)) * 8;                     // read-side slot offset
  // K staging: wave w stages d-chunks 2w,2w+1 for all 32 keys (2 rounds each)
  const u16* kst = Kb + (size_t)(b * S_ + (lane >> 2)) * KVD_ + kvh * D_ + wave * 64 + swz;
  // V staging: wave w stages d rows w*64..w*64+63 (4 rounds of 16 rows)
  const u16* vst = Vt + ((size_t)b << 22) + (size_t)(kvh * D_ + wave * 64 + (lane >> 2)) * S_ + swz;

  auto stage = [&](int kt, int bufi) {
    u16* kdst = &Ks[bufi][wave * 2048];
    u16* vdst = &Vs[bufi][wave * 2048];
    const u16* ksrc = kst + (size_t)(kt * 32) * KVD_;
#pragma unroll
    for (int c2 = 0; c2 < 2; c2++)
#pragma unroll
      for (int r = 0; r < 2; r++)
        gll16(ksrc + (size_t)(r * 16) * KVD_ + c2 * 32, kdst + c2 * 1024 + r * 512);
#pragma unroll
    for (int c = 0; c < 4; c++)
      gll16(vst + (size_t)(c * 16) * S_ + kt * 32, vdst + c * 512);
  };  // exactly 8 gll16 per wave per call

  stage(0, 0);
  for (int kt = 0; kt < nkt; kt++) {
    int cur = kt & 1;
    if (kt + 1 < nkt) {
      stage(kt + 1, cur ^ 1);                            // 8 loads stay in flight
      asm volatile("s_waitcnt vmcnt(8)" ::: "memory");   // cur's 8 loads landed
    } else {
      asm volatile("s_waitcnt vmcnt(0)" ::: "memory");
    }
    __builtin_amdgcn_s_barrier();                        // all waves' cur data in LDS
    asm volatile("" ::: "memory");

    // ---- QK: two 16x16 C-tiles over 8 d-chunks ----
    f32x4 sc0 = {}, sc1 = {};
#pragma unroll
    for (int c = 0; c < 8; c++) {
      bf16x8 k0 = *(const bf16x8*)(&Ks[cur][c * 1024 + l16 * 32 + rswz]);
      bf16x8 k1 = *(const bf16x8*)(&Ks[cur][c * 1024 + (l16 + 16) * 32 + rswz]);
      sc0 = __builtin_amdgcn_mfma_f32_16x16x32_bf16(qf[c], k0, sc0, 0, 0, 0);
      sc1 = __builtin_amdgcn_mfma_f32_16x16x32_bf16(qf[c], k1, sc1, 0, 0, 0);
    }

    // ---- online softmax with wave-uniform alpha-skip ----
    int kg0 = kt * 32 + l16, kg1 = kg0 + 16;
    float p0[4], p1[4], mnew[4];
    bool chg = false;
#pragma unroll
    for (int r = 0; r < 4; r++) {
      int qg = qw + quad * 4 + r;
      float a  = (kg0 <= qg) ? sc0[r] : -1e30f;
      float bb = (kg1 <= qg) ? sc1[r] : -1e30f;
      float mx = fmaxf(a, bb);
      for (int off = 1; off < 16; off <<= 1) mx = fmaxf(mx, __shfl_xor(mx, off, 16));
      float mn = fmaxf(m_r[r], mx);
      mnew[r] = mn;
      chg = chg || (mn > m_r[r]);
      p0[r] = __expf(a - mn);
      p1[r] = __expf(bb - mn);
    }
    if (__any((int)chg)) {   // alpha==1 exactly when no row max moved
      float alpha[4];
#pragma unroll
      for (int r = 0; r < 4; r++) alpha[r] = __expf(m_r[r] - mnew[r]);
#pragma unroll
      for (int nt = 0; nt < 16; nt++)
        for (int r = 0; r < 4; r++) o_acc[nt][r] *= alpha[r];
#pragma unroll
      for (int r = 0; r < 4; r++) l_r[r] *= alpha[r];
    }
#pragma unroll
    for (int r = 0; r < 4; r++) {
      m_r[r] = mnew[r];
      float rsum = p0[r] + p1[r];
      for (int off = 1; off < 16; off <<= 1) rsum += __shfl_xor(rsum, off, 16);
      l_r[r] += rsum;
    }

    // ---- P: C-layout -> LDS -> A-layout (same slot swizzle) ----
    u16* pw = &Ps[wave][0];
#pragma unroll
    for (int r = 0; r < 4; r++) {
      int row = quad * 4 + r;                    // row & 3 == r
      pw[row * 32 + (((l16 >> 3) ^ r) << 3) + (l16 & 7)] = f2bf(p0[r]);
      pw[row * 32 + ((((l16 >> 3) + 2) ^ r) << 3) + (l16 & 7)] = f2bf(p1[r]);
    }
    asm volatile("s_waitcnt lgkmcnt(0)" ::: "memory");
    bf16x8 pf = *(const bf16x8*)(&pw[l16 * 32 + rswz]);
#pragma unroll
    for (int nt = 0; nt < 16; nt++) {
      bf16x8 vf = *(const bf16x8*)(&Vs[cur][(nt * 16 + l16) * 32 + rswz]);
      o_acc[nt] = __builtin_amdgcn_mfma_f32_16x16x32_bf16(pf, vf, o_acc[nt], 0, 0, 0);
    }

    asm volatile("s_waitcnt lgkmcnt(0)" ::: "memory");   // LDS reads complete
    __builtin_amdgcn_s_barrier();                        // safe to overwrite cur next iter
    asm volatile("" ::: "memory");
  }
  // epilogue: O / l
  for (int r = 0; r < 4; r++) {
    int qg = qw + quad * 4 + r;
    float inv = 1.0f / l_r[r];
    u16* op = O + ((size_t)(b * S_) + qg) * HD_ + h * D_;
    for (int nt = 0; nt < 16; nt++) op[nt * 16 + l16] = f2bf(o_acc[nt][r] * inv);
  }
}

extern "C" void kernel_launch(void* const* d_in, const int* in_sizes, int n_in,
                              void* d_out, int out_size, void* d_ws, size_t ws_size,
                              hipStream_t stream) {
  const float* hs  = (const float*)d_in[0];
  const float* fc  = (const float*)d_in[1];
  const float* fsn = (const float*)d_in[2];
  // d_in[3] = mask: causal, replicated analytically
  const float* qw  = (const float*)d_in[4];
  const float* kw  = (const float*)d_in[5];
  const float* vw  = (const float*)d_in[6];
  const float* ow  = (const float*)d_in[7];
  const float* qnw = (const float*)d_in[8];
  const float* knw = (const float*)d_in[9];

  char* ws = (char*)d_ws;
  // layout (bytes):
  u16* x_bf = (u16*)(ws + 0);           // 4096*3072*2  = 25165824 (dead after GEMMs)
  u16* vt   = (u16*)(ws + 0);           // 2*2048*2048*2 = 16777216 (overlays dead x_bf)
  u16* qw_t = (u16*)(ws + 25165824);    // 4096*3072*2  = 25165824
  u16* kw_t = (u16*)(ws + 50331648);    // 2048*3072*2  = 12582912
  u16* vw_t = (u16*)(ws + 62914560);    // 2048*3072*2  = 12582912
  u16* ow_t = (u16*)(ws + 75497472);    // 3072*4096*2  = 25165824
  u16* xq   = (u16*)(ws + 100663296);   // 4096*4096*2  = 33554432
  u16* xk   = (u16*)(ws + 134217728);   // 4096*2048*2  = 16777216
  u16* xv   = (u16*)(ws + 150994944);   // 4096*2048*2  = 16777216  -> end 167772160
  u16* attn = (u16*)(ws + 25165824);    // overlays dead qw_t/kw_t region (33.5MB <= 37.7MB)

  cast_f32_bf16<<<12288, 256, 0, stream>>>(hs, x_bf, 4096 * 3072 / 4);
  transpose_cast<<<dim3(64, 48), 256, 0, stream>>>(qw, qw_t, 3072, 4096);
  transpose_cast<<<dim3(32, 48), 256, 0, stream>>>(kw, kw_t, 3072, 2048);
  transpose_cast<<<dim3(32, 48), 256, 0, stream>>>(vw, vw_t, 3072, 2048);
  transpose_cast<<<dim3(48, 64), 256, 0, stream>>>(ow, ow_t, 4096, 3072);

  gemm_bf16<false><<<dim3(32, 32), 256, 0, stream>>>(x_bf, qw_t, xq, 4096, 4096, 3072);
  gemm_bf16<false><<<dim3(16, 32), 256, 0, stream>>>(x_bf, kw_t, xk, 4096, 2048, 3072);
  gemm_bf16<false><<<dim3(16, 32), 256, 0, stream>>>(x_bf, vw_t, xv, 4096, 2048, 3072);

  rmsnorm_rope<<<dim3(4096, 4), 256, 0, stream>>>(xq, qnw, fc, fsn, 16, SCALE_);
  rmsnorm_rope<<<dim3(4096, 2), 256, 0, stream>>>(xk, knw, fc, fsn, 8, 1.0f);

  transpose_v<<<dim3(32, 64), 256, 0, stream>>>(xv, vt);

  flash_attn<<<dim3(32, 16, 2), 256, 0, stream>>>(xq, xk, vt, attn);

  gemm_bf16<true><<<dim3(24, 32), 256, 0, stream>>>(attn, ow_t, (float*)d_out, 4096, 3072, 4096);
}

// Round 2
// 971.349 us; speedup vs baseline: 1.0658x; 1.0619x over previous
//
#include <hip/hip_runtime.h>
#include <hip/hip_bf16.h>
#include <cstdint>

#define B_   2
#define S_   2048
#define HID_ 3072
#define H_   16
#define KV_  8
#define D_   256
#define HD_  4096   // H_*D_
#define KVD_ 2048   // KV_*D_

constexpr float EPS_   = 1e-6f;
constexpr float SCALE_ = 0.0625f;   // 256^-0.5

typedef unsigned short u16;
typedef __attribute__((ext_vector_type(8))) short bf16x8;
typedef __attribute__((ext_vector_type(4))) float f32x4;

__device__ inline float bf2f(u16 u) { return __uint_as_float(((unsigned int)u) << 16); }
__device__ inline u16 f2bf(float f) {
  unsigned int x = __float_as_uint(f);
  x += 0x7fffu + ((x >> 16) & 1u);   // RNE
  return (u16)(x >> 16);
}

// async global->LDS, 16B per lane; lds base must be wave-uniform, data lands at base + lane*16
__device__ inline void gll16(const u16* g, u16* l) {
  __builtin_amdgcn_global_load_lds((const __attribute__((address_space(1))) unsigned int*)g,
                                   (__attribute__((address_space(3))) unsigned int*)l,
                                   16, 0, 0);
}

// ---------------- elementwise cast f32 -> bf16 (n4 = n/4) ----------------
__global__ void cast_f32_bf16(const float* __restrict__ in, u16* __restrict__ out, int n4) {
  int i = blockIdx.x * blockDim.x + threadIdx.x;
  if (i < n4) {
    float4 v = ((const float4*)in)[i];
    ushort4 o;
    o.x = f2bf(v.x); o.y = f2bf(v.y); o.z = f2bf(v.z); o.w = f2bf(v.w);
    ((ushort4*)out)[i] = o;
  }
}

// ------------- transpose+cast: in[K][N] f32 -> out[N][K] bf16 -------------
__global__ void transpose_cast(const float* __restrict__ in, u16* __restrict__ out, int K, int N) {
  __shared__ __align__(16) float tile[64][65];
  int n0 = blockIdx.x * 64, k0 = blockIdx.y * 64;
  int t = threadIdx.x;
  int rr = t >> 4, cc = (t & 15) * 4;
  for (int i = 0; i < 4; i++) {
    float4 v = *(const float4*)(&in[(size_t)(k0 + rr + 16 * i) * N + n0 + cc]);
    tile[rr + 16 * i][cc + 0] = v.x; tile[rr + 16 * i][cc + 1] = v.y;
    tile[rr + 16 * i][cc + 2] = v.z; tile[rr + 16 * i][cc + 3] = v.w;
  }
  __syncthreads();
  for (int i = 0; i < 4; i++) {
    int orow = rr + 16 * i;  // n index
    ushort4 o;
    o.x = f2bf(tile[cc + 0][orow]); o.y = f2bf(tile[cc + 1][orow]);
    o.z = f2bf(tile[cc + 2][orow]); o.w = f2bf(tile[cc + 3][orow]);
    *(ushort4*)(&out[(size_t)(n0 + orow) * K + k0 + cc]) = o;
  }
}

// ------- bf16 transpose: in[4096 tok][2048 n] -> out[b][2048 n][2048 s] -------
__global__ void transpose_v(const u16* __restrict__ in, u16* __restrict__ out) {
  __shared__ __align__(16) u16 tile[64][68];
  int n0 = blockIdx.x * 64, tk0 = blockIdx.y * 64;
  int b = tk0 >> 11, s0 = tk0 & (S_ - 1);
  int t = threadIdx.x;
  int rr = t >> 4, cc = (t & 15) * 4;
  for (int i = 0; i < 4; i++) {
    ushort4 v = *(const ushort4*)(&in[(size_t)(tk0 + rr + 16 * i) * KVD_ + n0 + cc]);
    tile[rr + 16 * i][cc + 0] = v.x; tile[rr + 16 * i][cc + 1] = v.y;
    tile[rr + 16 * i][cc + 2] = v.z; tile[rr + 16 * i][cc + 3] = v.w;
  }
  __syncthreads();
  for (int i = 0; i < 4; i++) {
    int orow = rr + 16 * i;  // n index
    ushort4 o;
    o.x = tile[cc + 0][orow]; o.y = tile[cc + 1][orow];
    o.z = tile[cc + 2][orow]; o.w = tile[cc + 3][orow];
    *(ushort4*)(&out[((size_t)b << 22) + (size_t)(n0 + orow) * S_ + s0 + cc]) = o;
  }
}

// --------- GEMM: C[M][N] = A[M][K] * Bt[N][K]^T, bf16 in, f32 acc ---------
// m97 structure: 128x128 tile, BK=32, global_load_lds width-16, unpadded stride-32 LDS
template <bool OUTF32>
__global__ __launch_bounds__(256) void gemm_bf16(const u16* __restrict__ A,
                                                 const u16* __restrict__ Bt,
                                                 void* __restrict__ Cv, int M, int N, int K) {
  __shared__ __align__(16) u16 As[128 * 32];
  __shared__ __align__(16) u16 Bs[128 * 32];
  int t = threadIdx.x, lane = t & 63, wave = t >> 6;
  int wm = wave >> 1, wn = wave & 1, quad = lane >> 4, l16 = lane & 15;
  int bm = blockIdx.y * 128, bn = blockIdx.x * 128;
  f32x4 acc[4][4] = {};
  int srow = wave * 16 + (lane >> 2);
  int scol = (lane & 3) * 8;
  const u16* ap0 = A  + (size_t)(bm + srow) * K + scol;
  const u16* ap1 = A  + (size_t)(bm + 64 + srow) * K + scol;
  const u16* bp0 = Bt + (size_t)(bn + srow) * K + scol;
  const u16* bp1 = Bt + (size_t)(bn + 64 + srow) * K + scol;
  u16* asb0 = &As[wave * 512];
  u16* asb1 = &As[wave * 512 + 2048];
  u16* bsb0 = &Bs[wave * 512];
  u16* bsb1 = &Bs[wave * 512 + 2048];
  for (int k0 = 0; k0 < K; k0 += 32) {
    __syncthreads();
    gll16(ap0 + k0, asb0);
    gll16(ap1 + k0, asb1);
    gll16(bp0 + k0, bsb0);
    gll16(bp1 + k0, bsb1);
    __syncthreads();
    bf16x8 af[4], bfr[4];
    for (int i = 0; i < 4; i++)
      af[i] = *(const bf16x8*)(&As[(wm * 64 + i * 16 + l16) * 32 + quad * 8]);
    for (int j = 0; j < 4; j++)
      bfr[j] = *(const bf16x8*)(&Bs[(wn * 64 + j * 16 + l16) * 32 + quad * 8]);
    for (int i = 0; i < 4; i++)
      for (int j = 0; j < 4; j++)
        acc[i][j] = __builtin_amdgcn_mfma_f32_16x16x32_bf16(af[i], bfr[j], acc[i][j], 0, 0, 0);
  }
  for (int i = 0; i < 4; i++)
    for (int j = 0; j < 4; j++)
      for (int r = 0; r < 4; r++) {
        int row = bm + wm * 64 + i * 16 + quad * 4 + r;
        int col = bn + wn * 64 + j * 16 + l16;
        float v = acc[i][j][r];
        if (OUTF32) ((float*)Cv)[(size_t)row * N + col] = v;
        else ((u16*)Cv)[(size_t)row * N + col] = f2bf(v);
      }
}

// ----- fused RMSNorm + RoPE, in place on bf16 [B*S][nh][256]; 1 wave/head -----
__global__ void rmsnorm_rope(u16* __restrict__ x, const float* __restrict__ w,
                             const float* __restrict__ fc, const float* __restrict__ fsn,
                             int nh, float outscale) {
  int token = blockIdx.x;
  int head = blockIdx.y * 4 + (threadIdx.x >> 6);
  if (head >= nh) return;
  int lane = threadIdx.x & 63;
  int s = token & (S_ - 1);
  u16* p = x + (size_t)(token * nh + head) * D_;
  float v0 = bf2f(p[lane]);
  float v1 = bf2f(p[lane + 64]);
  float v2 = bf2f(p[lane + 128]);
  float v3 = bf2f(p[lane + 192]);
  float ss = v0 * v0 + v1 * v1 + v2 * v2 + v3 * v3;
  for (int off = 32; off; off >>= 1) ss += __shfl_xor(ss, off, 64);
  float rs = rsqrtf(ss * (1.0f / D_) + EPS_);
  float n0 = v0 * rs * (1.0f + w[lane]);
  float n1 = v1 * rs * (1.0f + w[lane + 64]);
  float n2 = v2 * rs * (1.0f + w[lane + 128]);
  float n3 = v3 * rs * (1.0f + w[lane + 192]);
  float c0 = fc[s * 128 + lane], s0 = fsn[s * 128 + lane];
  float c1 = fc[s * 128 + lane + 64], s1 = fsn[s * 128 + lane + 64];
  p[lane]       = f2bf((n0 * c0 - n2 * s0) * outscale);
  p[lane + 128] = f2bf((n0 * s0 + n2 * c0) * outscale);
  p[lane + 64]  = f2bf((n1 * c1 - n3 * s1) * outscale);
  p[lane + 192] = f2bf((n1 * s1 + n3 * c1) * outscale);
}

// ---------------- flash attention, causal, GQA rep=2, D=256 ----------------
// grid (S/64, H, B) longest-first; 256 threads; wave = 16 q rows; 32-key tiles.
// v3: swapped QK^T (C[key][q]) -> lane-local softmax row (q = l16); P->A-frag
//     via in-register 2-stage shfl butterfly (no Ps LDS roundtrip);
//     K double-buffered (early issue), V single-buffered (late issue),
//     counted vmcnt; LDS 48KB -> 3 blocks/CU.
__global__ __launch_bounds__(256, 3) void flash_attn(const u16* __restrict__ Q,
                                                     const u16* __restrict__ Kb,
                                                     const u16* __restrict__ Vt,
                                                     u16* __restrict__ O) {
  __shared__ __align__(16) u16 Ks[2][8 * 1024];   // [buf][chunk c][key 0..31][slot-swz 32 d]
  __shared__ __align__(16) u16 Vs[8 * 1024];      // [d 0..255][slot-swz 32 k]
  int t = threadIdx.x, lane = t & 63, wave = t >> 6;
  int quad = lane >> 4, l16 = lane & 15;
  int qb = ((int)gridDim.x - 1 - (int)blockIdx.x) * 64;  // longest blocks first
  int h = blockIdx.y, b = blockIdx.z;
  int kvh = h >> 1;
  int qw = qb + wave * 16;

  // Q fragments (B-layout: col = q = l16, k = quad*8..) straight from global
  bf16x8 qf[8];
  const u16* qp = Q + ((size_t)(b * S_) + qw + l16) * HD_ + h * D_;
#pragma unroll
  for (int c = 0; c < 8; c++) qf[c] = *(const bf16x8*)(qp + c * 32 + quad * 8);

  f32x4 o_acc[16] = {};
  float m_s = -3e38f, l_s = 0.f;    // per-lane softmax state for row q = qw + l16

  int nkt = (qb + 64) >> 5;
  // XOR slot swizzle (unchanged from v2): gll16 writes linearly, so the global
  // source slot is pre-swizzled per lane; reads apply the same XOR.
  int swz = ((lane & 3) ^ ((lane >> 2) & 3)) * 8;        // staging-side d/k offset
  int rswz = (quad ^ (l16 & 3)) * 8;                     // read-side slot offset
  const u16* kst = Kb + (size_t)(b * S_ + (lane >> 2)) * KVD_ + kvh * D_ + wave * 64 + swz;
  const u16* vst = Vt + ((size_t)b << 22) + (size_t)(kvh * D_ + wave * 64 + (lane >> 2)) * S_ + swz;

  auto stageK = [&](int kt, int bufi) {
    u16* kdst = &Ks[bufi][wave * 2048];
    const u16* ksrc = kst + (size_t)(kt * 32) * KVD_;
#pragma unroll
    for (int c2 = 0; c2 < 2; c2++)
#pragma unroll
      for (int r = 0; r < 2; r++)
        gll16(ksrc + (size_t)(r * 16) * KVD_ + c2 * 32, kdst + c2 * 1024 + r * 512);
  };  // 4 gll16
  auto stageV = [&](int kt) {
    u16* vdst = &Vs[wave * 2048];
#pragma unroll
    for (int c = 0; c < 4; c++)
      gll16(vst + (size_t)(c * 16) * S_ + kt * 32, vdst + c * 512);
  };  // 4 gll16

  stageK(0, 0);   // queue: [K(kt):4, V(kt):4] at each loop top
  stageV(0);
  for (int kt = 0; kt < nkt; kt++) {
    int cur = kt & 1;
    // own K(kt) landed (V(kt) may still be in flight: newest 4)
    asm volatile("s_waitcnt vmcnt(4)" ::: "memory");
    __builtin_amdgcn_s_barrier();                        // all waves' K(kt) in LDS
    asm volatile("" ::: "memory");
    if (kt + 1 < nkt) stageK(kt + 1, cur ^ 1);           // early issue, hides under QK+sm+PV

    // ---- QK (swapped): sc[key][q], key = kt*32 + (tile?16:0) + quad*4 + r, q = l16 ----
    f32x4 sc0 = {}, sc1 = {};
#pragma unroll
    for (int c = 0; c < 8; c++) {
      bf16x8 k0 = *(const bf16x8*)(&Ks[cur][c * 1024 + l16 * 32 + rswz]);
      bf16x8 k1 = *(const bf16x8*)(&Ks[cur][c * 1024 + (l16 + 16) * 32 + rswz]);
      sc0 = __builtin_amdgcn_mfma_f32_16x16x32_bf16(k0, qf[c], sc0, 0, 0, 0);
      sc1 = __builtin_amdgcn_mfma_f32_16x16x32_bf16(k1, qf[c], sc1, 0, 0, 0);
    }

    // ---- lane-local online softmax (row q = qw + l16) ----
    int qg = qw + l16;
    int kbase = kt * 32 + quad * 4;
    float p0[4], p1[4];
    float mx = -1e30f;
#pragma unroll
    for (int r = 0; r < 4; r++) {
      p0[r] = (kbase + r <= qg) ? sc0[r] : -1e30f;
      p1[r] = (kbase + 16 + r <= qg) ? sc1[r] : -1e30f;
      mx = fmaxf(mx, fmaxf(p0[r], p1[r]));
    }
    mx = fmaxf(mx, __shfl_xor(mx, 16));                  // reduce across quads
    mx = fmaxf(mx, __shfl_xor(mx, 32));
    float mn = fmaxf(m_s, mx);
    bool chg = mn > m_s;
    float rsum = 0.f;
#pragma unroll
    for (int r = 0; r < 4; r++) {
      p0[r] = __expf(p0[r] - mn);
      p1[r] = __expf(p1[r] - mn);
      rsum += p0[r] + p1[r];
    }
    if (__any((int)chg)) {
      float alpha = __expf(m_s - mn);                    // for q = qw + l16
      float ar[4];
#pragma unroll
      for (int r = 0; r < 4; r++) ar[r] = __shfl(alpha, quad * 20 + r);  // q' = quad*4+r
#pragma unroll
      for (int nt = 0; nt < 16; nt++)
#pragma unroll
        for (int r = 0; r < 4; r++) o_acc[nt][r] *= ar[r];
      l_s *= alpha;
    }
    m_s = mn;
    rsum += __shfl_xor(rsum, 16);
    rsum += __shfl_xor(rsum, 32);
    l_s += rsum;

    // ---- P: C-layout -> A-frag fully in-register (2-stage butterfly) ----
    // lane(l16,quad) holds keys {4q+r} (w0,w1) and {16+4q+r} (w2,w3), all for q=l16.
    // A-frag needs keys quad*8..quad*8+7 for row l16.
    unsigned int w_[4], x_[4], gl[4], gh[4], sn[4], rc[4];
    w_[0] = (unsigned)f2bf(p0[0]) | ((unsigned)f2bf(p0[1]) << 16);
    w_[1] = (unsigned)f2bf(p0[2]) | ((unsigned)f2bf(p0[3]) << 16);
    w_[2] = (unsigned)f2bf(p1[0]) | ((unsigned)f2bf(p1[1]) << 16);
    w_[3] = (unsigned)f2bf(p1[2]) | ((unsigned)f2bf(p1[3]) << 16);
#pragma unroll
    for (int i = 0; i < 4; i++) x_[i] = (unsigned)__shfl_xor((int)w_[i], 16);
    bool odd = (quad & 1) != 0;
    gl[0] = odd ? x_[0] : w_[0]; gl[1] = odd ? x_[1] : w_[1];
    gl[2] = odd ? w_[0] : x_[0]; gl[3] = odd ? w_[1] : x_[1];
    gh[0] = odd ? x_[2] : w_[2]; gh[1] = odd ? x_[3] : w_[3];
    gh[2] = odd ? w_[2] : x_[2]; gh[3] = odd ? w_[3] : x_[3];
#pragma unroll
    for (int i = 0; i < 4; i++) sn[i] = odd ? gl[i] : gh[i];
#pragma unroll
    for (int i = 0; i < 4; i++) rc[i] = (unsigned)__shfl_xor((int)sn[i], 32);
    union { unsigned int u[4]; bf16x8 v; } pfc;
#pragma unroll
    for (int i = 0; i < 4; i++)
      pfc.u[i] = (quad == 0) ? gl[i] : (quad == 3) ? gh[i] : rc[i];
    bf16x8 pf = pfc.v;

    // ---- V(kt) ready? own loads landed (K(kt+1) may be in flight), then barrier ----
    if (kt + 1 < nkt) asm volatile("s_waitcnt vmcnt(4)" ::: "memory");
    else              asm volatile("s_waitcnt vmcnt(0)" ::: "memory");
    __builtin_amdgcn_s_barrier();                        // all waves' V(kt) in LDS
    asm volatile("" ::: "memory");

    // ---- PV: O[q][d] += P * V ----
#pragma unroll
    for (int nt = 0; nt < 16; nt++) {
      bf16x8 vf = *(const bf16x8*)(&Vs[(nt * 16 + l16) * 32 + rswz]);
      o_acc[nt] = __builtin_amdgcn_mfma_f32_16x16x32_bf16(pf, vf, o_acc[nt], 0, 0, 0);
    }

    asm volatile("s_waitcnt lgkmcnt(0)" ::: "memory");   // Vs reads complete
    __builtin_amdgcn_s_barrier();                        // Vs free for next stage
    asm volatile("" ::: "memory");
    if (kt + 1 < nkt) stageV(kt + 1);                    // hides under next QK+sm
  }

  // epilogue: O / l  (l_s is for q = qw + l16; broadcast to O-layout rows quad*4+r)
  float invl = 1.0f / l_s;
  float inv_r[4];
#pragma unroll
  for (int r = 0; r < 4; r++) inv_r[r] = __shfl(invl, quad * 20 + r);
  for (int r = 0; r < 4; r++) {
    int qg2 = qw + quad * 4 + r;
    u16* op = O + ((size_t)(b * S_) + qg2) * HD_ + h * D_;
    for (int nt = 0; nt < 16; nt++) op[nt * 16 + l16] = f2bf(o_acc[nt][r] * inv_r[r]);
  }
}

extern "C" void kernel_launch(void* const* d_in, const int* in_sizes, int n_in,
                              void* d_out, int out_size, void* d_ws, size_t ws_size,
                              hipStream_t stream) {
  const float* hs  = (const float*)d_in[0];
  const float* fc  = (const float*)d_in[1];
  const float* fsn = (const float*)d_in[2];
  // d_in[3] = mask: causal, replicated analytically
  const float* qw  = (const float*)d_in[4];
  const float* kw  = (const float*)d_in[5];
  const float* vw  = (const float*)d_in[6];
  const float* ow  = (const float*)d_in[7];
  const float* qnw = (const float*)d_in[8];
  const float* knw = (const float*)d_in[9];

  char* ws = (char*)d_ws;
  // layout (bytes):
  u16* x_bf = (u16*)(ws + 0);           // 4096*3072*2  = 25165824 (dead after GEMMs)
  u16* vt   = (u16*)(ws + 0);           // 2*2048*2048*2 = 16777216 (overlays dead x_bf)
  u16* qw_t = (u16*)(ws + 25165824);    // 4096*3072*2  = 25165824
  u16* kw_t = (u16*)(ws + 50331648);    // 2048*3072*2  = 12582912
  u16* vw_t = (u16*)(ws + 62914560);    // 2048*3072*2  = 12582912
  u16* ow_t = (u16*)(ws + 75497472);    // 3072*4096*2  = 25165824
  u16* xq   = (u16*)(ws + 100663296);   // 4096*4096*2  = 33554432
  u16* xk   = (u16*)(ws + 134217728);   // 4096*2048*2  = 16777216
  u16* xv   = (u16*)(ws + 150994944);   // 4096*2048*2  = 16777216  -> end 167772160
  u16* attn = (u16*)(ws + 25165824);    // overlays dead qw_t/kw_t region (33.5MB <= 37.7MB)

  cast_f32_bf16<<<12288, 256, 0, stream>>>(hs, x_bf, 4096 * 3072 / 4);
  transpose_cast<<<dim3(64, 48), 256, 0, stream>>>(qw, qw_t, 3072, 4096);
  transpose_cast<<<dim3(32, 48), 256, 0, stream>>>(kw, kw_t, 3072, 2048);
  transpose_cast<<<dim3(32, 48), 256, 0, stream>>>(vw, vw_t, 3072, 2048);
  transpose_cast<<<dim3(48, 64), 256, 0, stream>>>(ow, ow_t, 4096, 3072);

  gemm_bf16<false><<<dim3(32, 32), 256, 0, stream>>>(x_bf, qw_t, xq, 4096, 4096, 3072);
  gemm_bf16<false><<<dim3(16, 32), 256, 0, stream>>>(x_bf, kw_t, xk, 4096, 2048, 3072);
  gemm_bf16<false><<<dim3(16, 32), 256, 0, stream>>>(x_bf, vw_t, xv, 4096, 2048, 3072);

  rmsnorm_rope<<<dim3(4096, 4), 256, 0, stream>>>(xq, qnw, fc, fsn, 16, SCALE_);
  rmsnorm_rope<<<dim3(4096, 2), 256, 0, stream>>>(xk, knw, fc, fsn, 8, 1.0f);

  transpose_v<<<dim3(32, 64), 256, 0, stream>>>(xv, vt);

  flash_attn<<<dim3(32, 16, 2), 256, 0, stream>>>(xq, xk, vt, attn);

  gemm_bf16<true><<<dim3(24, 32), 256, 0, stream>>>(attn, ow_t, (float*)d_out, 4096, 3072, 4096);
}

// Round 3
// 871.381 us; speedup vs baseline: 1.1880x; 1.1147x over previous
//
#include <hip/hip_runtime.h>
#include <hip/hip_bf16.h>
#include <cstdint>

#define B_   2
#define S_   2048
#define HID_ 3072
#define H_   16
#define KV_  8
#define D_   256
#define HD_  4096   // H_*D_
#define KVD_ 2048   // KV_*D_

constexpr float EPS_   = 1e-6f;
constexpr float SCALE_ = 0.0625f;   // 256^-0.5

typedef unsigned short u16;
typedef __attribute__((ext_vector_type(8))) short bf16x8;
typedef __attribute__((ext_vector_type(4))) float f32x4;

__device__ inline float bf2f(u16 u) { return __uint_as_float(((unsigned int)u) << 16); }
__device__ inline u16 f2bf(float f) {
  unsigned int x = __float_as_uint(f);
  x += 0x7fffu + ((x >> 16) & 1u);   // RNE
  return (u16)(x >> 16);
}

// async global->LDS, 16B per lane; lds base must be wave-uniform, data lands at base + lane*16
__device__ inline void gll16(const u16* g, u16* l) {
  __builtin_amdgcn_global_load_lds((const __attribute__((address_space(1))) unsigned int*)g,
                                   (__attribute__((address_space(3))) unsigned int*)l,
                                   16, 0, 0);
}

// ---------------- elementwise cast f32 -> bf16 (n4 = n/4) ----------------
__global__ void cast_f32_bf16(const float* __restrict__ in, u16* __restrict__ out, int n4) {
  int i = blockIdx.x * blockDim.x + threadIdx.x;
  if (i < n4) {
    float4 v = ((const float4*)in)[i];
    ushort4 o;
    o.x = f2bf(v.x); o.y = f2bf(v.y); o.z = f2bf(v.z); o.w = f2bf(v.w);
    ((ushort4*)out)[i] = o;
  }
}

// ------------- transpose+cast: in[K][N] f32 -> out[N][K] bf16 -------------
__global__ void transpose_cast(const float* __restrict__ in, u16* __restrict__ out, int K, int N) {
  __shared__ __align__(16) float tile[64][65];
  int n0 = blockIdx.x * 64, k0 = blockIdx.y * 64;
  int t = threadIdx.x;
  int rr = t >> 4, cc = (t & 15) * 4;
  for (int i = 0; i < 4; i++) {
    float4 v = *(const float4*)(&in[(size_t)(k0 + rr + 16 * i) * N + n0 + cc]);
    tile[rr + 16 * i][cc + 0] = v.x; tile[rr + 16 * i][cc + 1] = v.y;
    tile[rr + 16 * i][cc + 2] = v.z; tile[rr + 16 * i][cc + 3] = v.w;
  }
  __syncthreads();
  for (int i = 0; i < 4; i++) {
    int orow = rr + 16 * i;  // n index
    ushort4 o;
    o.x = f2bf(tile[cc + 0][orow]); o.y = f2bf(tile[cc + 1][orow]);
    o.z = f2bf(tile[cc + 2][orow]); o.w = f2bf(tile[cc + 3][orow]);
    *(ushort4*)(&out[(size_t)(n0 + orow) * K + k0 + cc]) = o;
  }
}

// ------- bf16 transpose: in[4096 tok][2048 n] -> out[b][2048 n][2048 s] -------
__global__ void transpose_v(const u16* __restrict__ in, u16* __restrict__ out) {
  __shared__ __align__(16) u16 tile[64][68];
  int n0 = blockIdx.x * 64, tk0 = blockIdx.y * 64;
  int b = tk0 >> 11, s0 = tk0 & (S_ - 1);
  int t = threadIdx.x;
  int rr = t >> 4, cc = (t & 15) * 4;
  for (int i = 0; i < 4; i++) {
    ushort4 v = *(const ushort4*)(&in[(size_t)(tk0 + rr + 16 * i) * KVD_ + n0 + cc]);
    tile[rr + 16 * i][cc + 0] = v.x; tile[rr + 16 * i][cc + 1] = v.y;
    tile[rr + 16 * i][cc + 2] = v.z; tile[rr + 16 * i][cc + 3] = v.w;
  }
  __syncthreads();
  for (int i = 0; i < 4; i++) {
    int orow = rr + 16 * i;  // n index
    ushort4 o;
    o.x = tile[cc + 0][orow]; o.y = tile[cc + 1][orow];
    o.z = tile[cc + 2][orow]; o.w = tile[cc + 3][orow];
    *(ushort4*)(&out[((size_t)b << 22) + (size_t)(n0 + orow) * S_ + s0 + cc]) = o;
  }
}

// --------- GEMM: C[M][N] = A[M][K] * Bt[N][K]^T, bf16 in, f32 acc ---------
// m97 structure: 128x128 tile, BK=32, global_load_lds width-16, unpadded stride-32 LDS
template <bool OUTF32>
__global__ __launch_bounds__(256) void gemm_bf16(const u16* __restrict__ A,
                                                 const u16* __restrict__ Bt,
                                                 void* __restrict__ Cv, int M, int N, int K) {
  __shared__ __align__(16) u16 As[128 * 32];
  __shared__ __align__(16) u16 Bs[128 * 32];
  int t = threadIdx.x, lane = t & 63, wave = t >> 6;
  int wm = wave >> 1, wn = wave & 1, quad = lane >> 4, l16 = lane & 15;
  int bm = blockIdx.y * 128, bn = blockIdx.x * 128;
  f32x4 acc[4][4] = {};
  int srow = wave * 16 + (lane >> 2);
  int scol = (lane & 3) * 8;
  const u16* ap0 = A  + (size_t)(bm + srow) * K + scol;
  const u16* ap1 = A  + (size_t)(bm + 64 + srow) * K + scol;
  const u16* bp0 = Bt + (size_t)(bn + srow) * K + scol;
  const u16* bp1 = Bt + (size_t)(bn + 64 + srow) * K + scol;
  u16* asb0 = &As[wave * 512];
  u16* asb1 = &As[wave * 512 + 2048];
  u16* bsb0 = &Bs[wave * 512];
  u16* bsb1 = &Bs[wave * 512 + 2048];
  for (int k0 = 0; k0 < K; k0 += 32) {
    __syncthreads();
    gll16(ap0 + k0, asb0);
    gll16(ap1 + k0, asb1);
    gll16(bp0 + k0, bsb0);
    gll16(bp1 + k0, bsb1);
    __syncthreads();
    bf16x8 af[4], bfr[4];
    for (int i = 0; i < 4; i++)
      af[i] = *(const bf16x8*)(&As[(wm * 64 + i * 16 + l16) * 32 + quad * 8]);
    for (int j = 0; j < 4; j++)
      bfr[j] = *(const bf16x8*)(&Bs[(wn * 64 + j * 16 + l16) * 32 + quad * 8]);
    for (int i = 0; i < 4; i++)
      for (int j = 0; j < 4; j++)
        acc[i][j] = __builtin_amdgcn_mfma_f32_16x16x32_bf16(af[i], bfr[j], acc[i][j], 0, 0, 0);
  }
  for (int i = 0; i < 4; i++)
    for (int j = 0; j < 4; j++)
      for (int r = 0; r < 4; r++) {
        int row = bm + wm * 64 + i * 16 + quad * 4 + r;
        int col = bn + wn * 64 + j * 16 + l16;
        float v = acc[i][j][r];
        if (OUTF32) ((float*)Cv)[(size_t)row * N + col] = v;
        else ((u16*)Cv)[(size_t)row * N + col] = f2bf(v);
      }
}

// ----- fused RMSNorm + RoPE, in place on bf16 [B*S][nh][256]; 1 wave/head -----
__global__ void rmsnorm_rope(u16* __restrict__ x, const float* __restrict__ w,
                             const float* __restrict__ fc, const float* __restrict__ fsn,
                             int nh, float outscale) {
  int token = blockIdx.x;
  int head = blockIdx.y * 4 + (threadIdx.x >> 6);
  if (head >= nh) return;
  int lane = threadIdx.x & 63;
  int s = token & (S_ - 1);
  u16* p = x + (size_t)(token * nh + head) * D_;
  float v0 = bf2f(p[lane]);
  float v1 = bf2f(p[lane + 64]);
  float v2 = bf2f(p[lane + 128]);
  float v3 = bf2f(p[lane + 192]);
  float ss = v0 * v0 + v1 * v1 + v2 * v2 + v3 * v3;
  for (int off = 32; off; off >>= 1) ss += __shfl_xor(ss, off, 64);
  float rs = rsqrtf(ss * (1.0f / D_) + EPS_);
  float n0 = v0 * rs * (1.0f + w[lane]);
  float n1 = v1 * rs * (1.0f + w[lane + 64]);
  float n2 = v2 * rs * (1.0f + w[lane + 128]);
  float n3 = v3 * rs * (1.0f + w[lane + 192]);
  float c0 = fc[s * 128 + lane], s0 = fsn[s * 128 + lane];
  float c1 = fc[s * 128 + lane + 64], s1 = fsn[s * 128 + lane + 64];
  p[lane]       = f2bf((n0 * c0 - n2 * s0) * outscale);
  p[lane + 128] = f2bf((n0 * s0 + n2 * c0) * outscale);
  p[lane + 64]  = f2bf((n1 * c1 - n3 * s1) * outscale);
  p[lane + 192] = f2bf((n1 * s1 + n3 * c1) * outscale);
}

// ---------------- flash attention, causal, GQA rep=2, D=256 ----------------
// v4: causal work-pairing. grid (16, H, B); block bx handles q-tiles (31-bx)
//     then bx -> every block runs exactly 66 key-iterations (uniform load,
//     no tail). 256 threads; wave = 16 q rows; 32-key tiles; swapped-QK
//     lane-local softmax; in-register P butterfly; K dbuf / V sbuf staging
//     with counted vmcnt.
__global__ __launch_bounds__(256, 3) void flash_attn(const u16* __restrict__ Q,
                                                     const u16* __restrict__ Kb,
                                                     const u16* __restrict__ Vt,
                                                     u16* __restrict__ O) {
  __shared__ __align__(16) u16 Ks[2][8 * 1024];   // [buf][chunk c][key 0..31][slot-swz 32 d]
  __shared__ __align__(16) u16 Vs[8 * 1024];      // [d 0..255][slot-swz 32 k]
  int t = threadIdx.x, lane = t & 63, wave = t >> 6;
  int quad = lane >> 4, l16 = lane & 15;
  int h = blockIdx.y, b = blockIdx.z;
  int kvh = h >> 1;

  // XOR slot swizzle: gll16 writes linearly, so the global source slot is
  // pre-swizzled per lane; reads apply the same XOR.
  int swz = ((lane & 3) ^ ((lane >> 2) & 3)) * 8;        // staging-side d/k offset
  int rswz = (quad ^ (l16 & 3)) * 8;                     // read-side slot offset
  const u16* kst = Kb + (size_t)(b * S_ + (lane >> 2)) * KVD_ + kvh * D_ + wave * 64 + swz;
  const u16* vst = Vt + ((size_t)b << 22) + (size_t)(kvh * D_ + wave * 64 + (lane >> 2)) * S_ + swz;

  auto stageK = [&](int kt, int bufi) {
    u16* kdst = &Ks[bufi][wave * 2048];
    const u16* ksrc = kst + (size_t)(kt * 32) * KVD_;
#pragma unroll
    for (int c2 = 0; c2 < 2; c2++)
#pragma unroll
      for (int r = 0; r < 2; r++)
        gll16(ksrc + (size_t)(r * 16) * KVD_ + c2 * 32, kdst + c2 * 1024 + r * 512);
  };  // 4 gll16
  auto stageV = [&](int kt) {
    u16* vdst = &Vs[wave * 2048];
#pragma unroll
    for (int c = 0; c < 4; c++)
      gll16(vst + (size_t)(c * 16) * S_ + kt * 32, vdst + c * 512);
  };  // 4 gll16

#pragma unroll 1
  for (int half = 0; half < 2; half++) {
    // big q-tile first, then the paired small one: iters (64-2bx) + (2bx+2) = 66
    int qb = (half == 0) ? (31 - (int)blockIdx.x) * 64 : (int)blockIdx.x * 64;
    int qw = qb + wave * 16;

    // Q fragments (B-layout: col = q = l16, k = quad*8..) straight from global
    bf16x8 qf[8];
    const u16* qp = Q + ((size_t)(b * S_) + qw + l16) * HD_ + h * D_;
#pragma unroll
    for (int c = 0; c < 8; c++) qf[c] = *(const bf16x8*)(qp + c * 32 + quad * 8);

    f32x4 o_acc[16] = {};
    float m_s = -3e38f, l_s = 0.f;    // per-lane softmax state for row q = qw + l16

    int nkt = (qb + 64) >> 5;
    stageK(0, 0);   // queue: [K(kt):4, V(kt):4] at each loop top
    stageV(0);
#pragma unroll 1
    for (int kt = 0; kt < nkt; kt++) {
      int cur = kt & 1;
      // own K(kt) landed (V(kt) may still be in flight: newest 4)
      asm volatile("s_waitcnt vmcnt(4)" ::: "memory");
      __builtin_amdgcn_s_barrier();                        // all waves' K(kt) in LDS
      asm volatile("" ::: "memory");
      if (kt + 1 < nkt) stageK(kt + 1, cur ^ 1);           // early issue

      // ---- QK (swapped): sc[key][q], key = kt*32 + (tile?16:0) + quad*4 + r, q = l16 ----
      f32x4 sc0 = {}, sc1 = {};
#pragma unroll
      for (int c = 0; c < 8; c++) {
        bf16x8 k0 = *(const bf16x8*)(&Ks[cur][c * 1024 + l16 * 32 + rswz]);
        bf16x8 k1 = *(const bf16x8*)(&Ks[cur][c * 1024 + (l16 + 16) * 32 + rswz]);
        sc0 = __builtin_amdgcn_mfma_f32_16x16x32_bf16(k0, qf[c], sc0, 0, 0, 0);
        sc1 = __builtin_amdgcn_mfma_f32_16x16x32_bf16(k1, qf[c], sc1, 0, 0, 0);
      }

      // ---- lane-local online softmax (row q = qw + l16) ----
      int qg = qw + l16;
      int kbase = kt * 32 + quad * 4;
      float p0[4], p1[4];
      float mx = -1e30f;
#pragma unroll
      for (int r = 0; r < 4; r++) {
        p0[r] = (kbase + r <= qg) ? sc0[r] : -1e30f;
        p1[r] = (kbase + 16 + r <= qg) ? sc1[r] : -1e30f;
        mx = fmaxf(mx, fmaxf(p0[r], p1[r]));
      }
      mx = fmaxf(mx, __shfl_xor(mx, 16));                  // reduce across quads
      mx = fmaxf(mx, __shfl_xor(mx, 32));
      float mn = fmaxf(m_s, mx);
      bool chg = mn > m_s;
      float rsum = 0.f;
#pragma unroll
      for (int r = 0; r < 4; r++) {
        p0[r] = __expf(p0[r] - mn);
        p1[r] = __expf(p1[r] - mn);
        rsum += p0[r] + p1[r];
      }
      if (__any((int)chg)) {
        float alpha = __expf(m_s - mn);                    // for q = qw + l16
        float ar[4];
#pragma unroll
        for (int r = 0; r < 4; r++) ar[r] = __shfl(alpha, quad * 20 + r);  // q' = quad*4+r
#pragma unroll
        for (int nt = 0; nt < 16; nt++)
#pragma unroll
          for (int r = 0; r < 4; r++) o_acc[nt][r] *= ar[r];
        l_s *= alpha;
      }
      m_s = mn;
      rsum += __shfl_xor(rsum, 16);
      rsum += __shfl_xor(rsum, 32);
      l_s += rsum;

      // ---- P: C-layout -> A-frag fully in-register (2-stage butterfly) ----
      unsigned int w_[4], x_[4], gl[4], gh[4], sn[4], rc[4];
      w_[0] = (unsigned)f2bf(p0[0]) | ((unsigned)f2bf(p0[1]) << 16);
      w_[1] = (unsigned)f2bf(p0[2]) | ((unsigned)f2bf(p0[3]) << 16);
      w_[2] = (unsigned)f2bf(p1[0]) | ((unsigned)f2bf(p1[1]) << 16);
      w_[3] = (unsigned)f2bf(p1[2]) | ((unsigned)f2bf(p1[3]) << 16);
#pragma unroll
      for (int i = 0; i < 4; i++) x_[i] = (unsigned)__shfl_xor((int)w_[i], 16);
      bool odd = (quad & 1) != 0;
      gl[0] = odd ? x_[0] : w_[0]; gl[1] = odd ? x_[1] : w_[1];
      gl[2] = odd ? w_[0] : x_[0]; gl[3] = odd ? w_[1] : x_[1];
      gh[0] = odd ? x_[2] : w_[2]; gh[1] = odd ? x_[3] : w_[3];
      gh[2] = odd ? w_[2] : x_[2]; gh[3] = odd ? w_[3] : x_[3];
#pragma unroll
      for (int i = 0; i < 4; i++) sn[i] = odd ? gl[i] : gh[i];
#pragma unroll
      for (int i = 0; i < 4; i++) rc[i] = (unsigned)__shfl_xor((int)sn[i], 32);
      union { unsigned int u[4]; bf16x8 v; } pfc;
#pragma unroll
      for (int i = 0; i < 4; i++)
        pfc.u[i] = (quad == 0) ? gl[i] : (quad == 3) ? gh[i] : rc[i];
      bf16x8 pf = pfc.v;

      // ---- V(kt) ready? own loads landed (K(kt+1) may be in flight) ----
      if (kt + 1 < nkt) asm volatile("s_waitcnt vmcnt(4)" ::: "memory");
      else              asm volatile("s_waitcnt vmcnt(0)" ::: "memory");
      __builtin_amdgcn_s_barrier();                        // all waves' V(kt) in LDS
      asm volatile("" ::: "memory");

      // ---- PV: O[q][d] += P * V ----
#pragma unroll
      for (int nt = 0; nt < 16; nt++) {
        bf16x8 vf = *(const bf16x8*)(&Vs[(nt * 16 + l16) * 32 + rswz]);
        o_acc[nt] = __builtin_amdgcn_mfma_f32_16x16x32_bf16(pf, vf, o_acc[nt], 0, 0, 0);
      }

      asm volatile("s_waitcnt lgkmcnt(0)" ::: "memory");   // Vs reads complete
      __builtin_amdgcn_s_barrier();                        // Vs free for next stage
      asm volatile("" ::: "memory");
      if (kt + 1 < nkt) stageV(kt + 1);                    // hides under next QK+sm
    }

    // epilogue: O / l  (l_s is for q = qw + l16; broadcast to rows quad*4+r)
    float invl = 1.0f / l_s;
    float inv_r[4];
#pragma unroll
    for (int r = 0; r < 4; r++) inv_r[r] = __shfl(invl, quad * 20 + r);
    for (int r = 0; r < 4; r++) {
      int qg2 = qw + quad * 4 + r;
      u16* op = O + ((size_t)(b * S_) + qg2) * HD_ + h * D_;
      for (int nt = 0; nt < 16; nt++) op[nt * 16 + l16] = f2bf(o_acc[nt][r] * inv_r[r]);
    }
  }
}

extern "C" void kernel_launch(void* const* d_in, const int* in_sizes, int n_in,
                              void* d_out, int out_size, void* d_ws, size_t ws_size,
                              hipStream_t stream) {
  const float* hs  = (const float*)d_in[0];
  const float* fc  = (const float*)d_in[1];
  const float* fsn = (const float*)d_in[2];
  // d_in[3] = mask: causal, replicated analytically
  const float* qw  = (const float*)d_in[4];
  const float* kw  = (const float*)d_in[5];
  const float* vw  = (const float*)d_in[6];
  const float* ow  = (const float*)d_in[7];
  const float* qnw = (const float*)d_in[8];
  const float* knw = (const float*)d_in[9];

  char* ws = (char*)d_ws;
  // layout (bytes):
  u16* x_bf = (u16*)(ws + 0);           // 4096*3072*2  = 25165824 (dead after GEMMs)
  u16* vt   = (u16*)(ws + 0);           // 2*2048*2048*2 = 16777216 (overlays dead x_bf)
  u16* qw_t = (u16*)(ws + 25165824);    // 4096*3072*2  = 25165824
  u16* kw_t = (u16*)(ws + 50331648);    // 2048*3072*2  = 12582912
  u16* vw_t = (u16*)(ws + 62914560);    // 2048*3072*2  = 12582912
  u16* ow_t = (u16*)(ws + 75497472);    // 3072*4096*2  = 25165824
  u16* xq   = (u16*)(ws + 100663296);   // 4096*4096*2  = 33554432
  u16* xk   = (u16*)(ws + 134217728);   // 4096*2048*2  = 16777216
  u16* xv   = (u16*)(ws + 150994944);   // 4096*2048*2  = 16777216  -> end 167772160
  u16* attn = (u16*)(ws + 25165824);    // overlays dead qw_t/kw_t region (33.5MB <= 37.7MB)

  cast_f32_bf16<<<12288, 256, 0, stream>>>(hs, x_bf, 4096 * 3072 / 4);
  transpose_cast<<<dim3(64, 48), 256, 0, stream>>>(qw, qw_t, 3072, 4096);
  transpose_cast<<<dim3(32, 48), 256, 0, stream>>>(kw, kw_t, 3072, 2048);
  transpose_cast<<<dim3(32, 48), 256, 0, stream>>>(vw, vw_t, 3072, 2048);
  transpose_cast<<<dim3(48, 64), 256, 0, stream>>>(ow, ow_t, 4096, 3072);

  gemm_bf16<false><<<dim3(32, 32), 256, 0, stream>>>(x_bf, qw_t, xq, 4096, 4096, 3072);
  gemm_bf16<false><<<dim3(16, 32), 256, 0, stream>>>(x_bf, kw_t, xk, 4096, 2048, 3072);
  gemm_bf16<false><<<dim3(16, 32), 256, 0, stream>>>(x_bf, vw_t, xv, 4096, 2048, 3072);

  rmsnorm_rope<<<dim3(4096, 4), 256, 0, stream>>>(xq, qnw, fc, fsn, 16, SCALE_);
  rmsnorm_rope<<<dim3(4096, 2), 256, 0, stream>>>(xk, knw, fc, fsn, 8, 1.0f);

  transpose_v<<<dim3(32, 64), 256, 0, stream>>>(xv, vt);

  flash_attn<<<dim3(16, 16, 2), 256, 0, stream>>>(xq, xk, vt, attn);

  gemm_bf16<true><<<dim3(24, 32), 256, 0, stream>>>(attn, ow_t, (float*)d_out, 4096, 3072, 4096);
}

// Round 4
// 769.470 us; speedup vs baseline: 1.3454x; 1.1324x over previous
//
#include <hip/hip_runtime.h>
#include <hip/hip_bf16.h>
#include <cstdint>

#define B_   2
#define S_   2048
#define HID_ 3072
#define H_   16
#define KV_  8
#define D_   256
#define HD_  4096   // H_*D_
#define KVD_ 2048   // KV_*D_
#define QKS_ 8192   // merged qkv row stride

constexpr float EPS_   = 1e-6f;
constexpr float SCALE_ = 0.0625f;   // 256^-0.5

typedef unsigned short u16;
typedef __attribute__((ext_vector_type(8))) short bf16x8;
typedef __attribute__((ext_vector_type(4))) float f32x4;

__device__ inline float bf2f(u16 u) { return __uint_as_float(((unsigned int)u) << 16); }
__device__ inline u16 f2bf(float f) {
  unsigned int x = __float_as_uint(f);
  x += 0x7fffu + ((x >> 16) & 1u);   // RNE
  return (u16)(x >> 16);
}

// async global->LDS, 16B per lane; lds base must be wave-uniform, data lands at base + lane*16
__device__ inline void gll16(const u16* g, u16* l) {
  __builtin_amdgcn_global_load_lds((const __attribute__((address_space(1))) unsigned int*)g,
                                   (__attribute__((address_space(3))) unsigned int*)l,
                                   16, 0, 0);
}

// ---------------- elementwise cast f32 -> bf16 (n4 = n/4) ----------------
__global__ void cast_f32_bf16(const float* __restrict__ in, u16* __restrict__ out, int n4) {
  int i = blockIdx.x * blockDim.x + threadIdx.x;
  if (i < n4) {
    float4 v = ((const float4*)in)[i];
    ushort4 o;
    o.x = f2bf(v.x); o.y = f2bf(v.y); o.z = f2bf(v.z); o.w = f2bf(v.w);
    ((ushort4*)out)[i] = o;
  }
}

// ------------- transpose+cast: in[K][N] f32 -> out[N][K] bf16 -------------
__global__ void transpose_cast(const float* __restrict__ in, u16* __restrict__ out, int K, int N) {
  __shared__ __align__(16) float tile[64][65];
  int n0 = blockIdx.x * 64, k0 = blockIdx.y * 64;
  int t = threadIdx.x;
  int rr = t >> 4, cc = (t & 15) * 4;
  for (int i = 0; i < 4; i++) {
    float4 v = *(const float4*)(&in[(size_t)(k0 + rr + 16 * i) * N + n0 + cc]);
    tile[rr + 16 * i][cc + 0] = v.x; tile[rr + 16 * i][cc + 1] = v.y;
    tile[rr + 16 * i][cc + 2] = v.z; tile[rr + 16 * i][cc + 3] = v.w;
  }
  __syncthreads();
  for (int i = 0; i < 4; i++) {
    int orow = rr + 16 * i;  // n index
    ushort4 o;
    o.x = f2bf(tile[cc + 0][orow]); o.y = f2bf(tile[cc + 1][orow]);
    o.z = f2bf(tile[cc + 2][orow]); o.w = f2bf(tile[cc + 3][orow]);
    *(ushort4*)(&out[(size_t)(n0 + orow) * K + k0 + cc]) = o;
  }
}

// ----- bf16 transpose: in (xqkv V cols, stride 8192) -> out[b][2048 n][2048 s] -----
__global__ void transpose_v(const u16* __restrict__ in, u16* __restrict__ out) {
  __shared__ __align__(16) u16 tile[64][68];
  int n0 = blockIdx.x * 64, tk0 = blockIdx.y * 64;
  int b = tk0 >> 11, s0 = tk0 & (S_ - 1);
  int t = threadIdx.x;
  int rr = t >> 4, cc = (t & 15) * 4;
  for (int i = 0; i < 4; i++) {
    ushort4 v = *(const ushort4*)(&in[(size_t)(tk0 + rr + 16 * i) * QKS_ + n0 + cc]);
    tile[rr + 16 * i][cc + 0] = v.x; tile[rr + 16 * i][cc + 1] = v.y;
    tile[rr + 16 * i][cc + 2] = v.z; tile[rr + 16 * i][cc + 3] = v.w;
  }
  __syncthreads();
  for (int i = 0; i < 4; i++) {
    int orow = rr + 16 * i;  // n index
    ushort4 o;
    o.x = tile[cc + 0][orow]; o.y = tile[cc + 1][orow];
    o.z = tile[cc + 2][orow]; o.w = tile[cc + 3][orow];
    *(ushort4*)(&out[((size_t)b << 22) + (size_t)(n0 + orow) * S_ + s0 + cc]) = o;
  }
}

// ===== 256x256 8-wave 4-phase GEMM: C[M][N] = A[M][K] * Bt[N][K]^T =====
// BK=64, double-buffered 128KB LDS in [subtile 16x32]-chunks, slot-swizzled
// (phys = slot ^ ((row>>1)&3)) via pre-swizzled global source; stages during
// K-tile t target t+2 (same buffer, region staged one phase after its last
// read -> WAR-safe); counted vmcnt(8) once per tile; setprio around MFMA.
template <bool OUTF32>
__global__ __launch_bounds__(512, 2) void gemm256(const u16* __restrict__ A,
                                                  const u16* __restrict__ Bt,
                                                  void* __restrict__ Cv, int M, int N, int K) {
  __shared__ __align__(16) u16 As[2][16384];
  __shared__ __align__(16) u16 Bs[2][16384];
  int t = threadIdx.x, lane = t & 63, wave = t >> 6;
  int quad = lane >> 4, l16 = lane & 15;
  int wm = wave >> 2, wn = wave & 3;

  // XCD-chunked bid swizzle (requires nwg % 8 == 0; 512 and 192 both qualify)
  int nwg = gridDim.x * gridDim.y;
  int bid = blockIdx.y * gridDim.x + blockIdx.x;
  int sbid = (bid & 7) * (nwg >> 3) + (bid >> 3);
  int bn = (sbid % gridDim.x) * 256;
  int bm = (sbid / gridDim.x) * 256;

  // staging: one gll16 fills one 16x32 subtile (1KB); lane l -> row l>>2,
  // phys slot l&3 holding logical slot (l&3)^((l>>3)&3)
  int srow = lane >> 2;
  int scol8 = ((lane & 3) ^ ((lane >> 3) & 3)) * 8;
  const u16* ap = A + (size_t)(bm + srow) * K + scol8;
  const u16* bp = Bt + (size_t)(bn + srow) * K + scol8;
  int ha1 = (wave & 3) + ((wave >> 2) << 3);   // {0,1,2,3,8,9,10,11}
  int hb1 = (wave & 1) + ((wave >> 1) << 2);   // {0,1,4,5,8,9,12,13}

  auto stA = [&](int sr, int sc, int k0, int bufi) {
    gll16(ap + (size_t)(sr * 16) * K + k0 + sc * 32, &As[bufi][(sr * 2 + sc) * 512]);
  };
  auto stB = [&](int sr, int sc, int k0, int bufi) {
    gll16(bp + (size_t)(sr * 16) * K + k0 + sc * 32, &Bs[bufi][(sr * 2 + sc) * 512]);
  };

  // frag read offset within a subtile (2-way banks: slot = quad ^ ((l16>>1)&3))
  int rsw = l16 * 32 + ((quad ^ ((l16 >> 1) & 3)) * 8);
#define LDA8(i, ks) (*(const bf16x8*)(&As[cur][((wm * 8 + (i)) * 2 + (ks)) * 512 + rsw]))
#define LDB8(j, ks) (*(const bf16x8*)(&Bs[cur][((wn * 4 + (j)) * 2 + (ks)) * 512 + rsw]))

  f32x4 acc[8][4] = {};
  int NT = K >> 6;

  // prologue: stage K-tiles 0,1 fully (8 gll16 each per wave)
#pragma unroll
  for (int h = 0; h < 2; h++) {
    int k0 = h * 64;
    stA(ha1, 0, k0, h); stA(ha1, 1, k0, h);
    stA(ha1 + 4, 0, k0, h); stA(ha1 + 4, 1, k0, h);
    stB(hb1, 0, k0, h); stB(hb1, 1, k0, h);
    stB(hb1 + 2, 0, k0, h); stB(hb1 + 2, 1, k0, h);
  }
  asm volatile("s_waitcnt vmcnt(8)" ::: "memory");   // tile 0 landed
  __builtin_amdgcn_s_barrier();
  asm volatile("" ::: "memory");

#pragma unroll 1
  for (int kt = 0; kt < NT; kt++) {
    int cur = kt & 1;
    int kp = (kt + 2) * 64;
    bool pre = (kt + 2) < NT;
    bf16x8 a[4][2], b[4][2];
    // ---- ph1: read A m-half0 + B n-half0; MFMA quadrant (m0,n01) ----
#pragma unroll
    for (int i = 0; i < 4; i++) { a[i][0] = LDA8(i, 0); a[i][1] = LDA8(i, 1); }
#pragma unroll
    for (int j = 0; j < 2; j++) { b[j][0] = LDB8(j, 0); b[j][1] = LDB8(j, 1); }
    __builtin_amdgcn_s_barrier();
    asm volatile("s_waitcnt lgkmcnt(0)" ::: "memory");
    __builtin_amdgcn_sched_barrier(0);
    __builtin_amdgcn_s_setprio(1);
#pragma unroll
    for (int i = 0; i < 4; i++)
#pragma unroll
      for (int j = 0; j < 2; j++) {
        acc[i][j] = __builtin_amdgcn_mfma_f32_16x16x32_bf16(a[i][0], b[j][0], acc[i][j], 0, 0, 0);
        acc[i][j] = __builtin_amdgcn_mfma_f32_16x16x32_bf16(a[i][1], b[j][1], acc[i][j], 0, 0, 0);
      }
    __builtin_amdgcn_s_setprio(0);
    // ---- ph2: read B n-half1; stage HA1+HB1(t+2); MFMA (m0,n23) ----
#pragma unroll
    for (int j = 2; j < 4; j++) { b[j][0] = LDB8(j, 0); b[j][1] = LDB8(j, 1); }
    if (pre) { stA(ha1, 0, kp, cur); stA(ha1, 1, kp, cur);
               stB(hb1, 0, kp, cur); stB(hb1, 1, kp, cur); }
    __builtin_amdgcn_s_barrier();
    asm volatile("s_waitcnt lgkmcnt(0)" ::: "memory");
    __builtin_amdgcn_sched_barrier(0);
    __builtin_amdgcn_s_setprio(1);
#pragma unroll
    for (int i = 0; i < 4; i++)
#pragma unroll
      for (int j = 2; j < 4; j++) {
        acc[i][j] = __builtin_amdgcn_mfma_f32_16x16x32_bf16(a[i][0], b[j][0], acc[i][j], 0, 0, 0);
        acc[i][j] = __builtin_amdgcn_mfma_f32_16x16x32_bf16(a[i][1], b[j][1], acc[i][j], 0, 0, 0);
      }
    __builtin_amdgcn_s_setprio(0);
    // ---- ph3: read A m-half1; stage HB2(t+2); MFMA (m1,n23) ----
#pragma unroll
    for (int i = 0; i < 4; i++) { a[i][0] = LDA8(i + 4, 0); a[i][1] = LDA8(i + 4, 1); }
    if (pre) { stB(hb1 + 2, 0, kp, cur); stB(hb1 + 2, 1, kp, cur); }
    __builtin_amdgcn_s_barrier();
    asm volatile("s_waitcnt lgkmcnt(0)" ::: "memory");
    __builtin_amdgcn_sched_barrier(0);
    __builtin_amdgcn_s_setprio(1);
#pragma unroll
    for (int i = 0; i < 4; i++)
#pragma unroll
      for (int j = 2; j < 4; j++) {
        acc[i + 4][j] = __builtin_amdgcn_mfma_f32_16x16x32_bf16(a[i][0], b[j][0], acc[i + 4][j], 0, 0, 0);
        acc[i + 4][j] = __builtin_amdgcn_mfma_f32_16x16x32_bf16(a[i][1], b[j][1], acc[i + 4][j], 0, 0, 0);
      }
    __builtin_amdgcn_s_setprio(0);
    // ---- ph4: stage HA2(t+2); MFMA (m1,n01); vmcnt gate ----
    if (pre) { stA(ha1 + 4, 0, kp, cur); stA(ha1 + 4, 1, kp, cur); }
    __builtin_amdgcn_s_setprio(1);
#pragma unroll
    for (int i = 0; i < 4; i++)
#pragma unroll
      for (int j = 0; j < 2; j++) {
        acc[i + 4][j] = __builtin_amdgcn_mfma_f32_16x16x32_bf16(a[i][0], b[j][0], acc[i + 4][j], 0, 0, 0);
        acc[i + 4][j] = __builtin_amdgcn_mfma_f32_16x16x32_bf16(a[i][1], b[j][1], acc[i + 4][j], 0, 0, 0);
      }
    __builtin_amdgcn_s_setprio(0);
    asm volatile("s_waitcnt vmcnt(8)" ::: "memory");     // tile t+1 fully landed
    __builtin_amdgcn_s_barrier();
    asm volatile("" ::: "memory");
  }

  // epilogue
#pragma unroll
  for (int i = 0; i < 8; i++)
#pragma unroll
    for (int j = 0; j < 4; j++)
#pragma unroll
      for (int r = 0; r < 4; r++) {
        int row = bm + wm * 128 + i * 16 + quad * 4 + r;
        int col = bn + wn * 64 + j * 16 + l16;
        float v = acc[i][j][r];
        if (OUTF32) ((float*)Cv)[(size_t)row * N + col] = v;
        else ((u16*)Cv)[(size_t)row * N + col] = f2bf(v);
      }
#undef LDA8
#undef LDB8
}

// ----- fused RMSNorm + RoPE, in place on bf16 [token][stride]; 1 wave/head -----
__global__ void rmsnorm_rope(u16* __restrict__ x, const float* __restrict__ w,
                             const float* __restrict__ fc, const float* __restrict__ fsn,
                             int nh, int stride, float outscale) {
  int token = blockIdx.x;
  int head = blockIdx.y * 4 + (threadIdx.x >> 6);
  if (head >= nh) return;
  int lane = threadIdx.x & 63;
  int s = token & (S_ - 1);
  u16* p = x + (size_t)token * stride + head * D_;
  float v0 = bf2f(p[lane]);
  float v1 = bf2f(p[lane + 64]);
  float v2 = bf2f(p[lane + 128]);
  float v3 = bf2f(p[lane + 192]);
  float ss = v0 * v0 + v1 * v1 + v2 * v2 + v3 * v3;
  for (int off = 32; off; off >>= 1) ss += __shfl_xor(ss, off, 64);
  float rs = rsqrtf(ss * (1.0f / D_) + EPS_);
  float n0 = v0 * rs * (1.0f + w[lane]);
  float n1 = v1 * rs * (1.0f + w[lane + 64]);
  float n2 = v2 * rs * (1.0f + w[lane + 128]);
  float n3 = v3 * rs * (1.0f + w[lane + 192]);
  float c0 = fc[s * 128 + lane], s0 = fsn[s * 128 + lane];
  float c1 = fc[s * 128 + lane + 64], s1 = fsn[s * 128 + lane + 64];
  p[lane]       = f2bf((n0 * c0 - n2 * s0) * outscale);
  p[lane + 128] = f2bf((n0 * s0 + n2 * c0) * outscale);
  p[lane + 64]  = f2bf((n1 * c1 - n3 * s1) * outscale);
  p[lane + 192] = f2bf((n1 * s1 + n3 * c1) * outscale);
}

// ---------------- flash attention, causal, GQA rep=2, D=256 ----------------
// v4 + merged-qkv strides: Q/K rows have stride 8192.
__global__ __launch_bounds__(256, 3) void flash_attn(const u16* __restrict__ Q,
                                                     const u16* __restrict__ Kb,
                                                     const u16* __restrict__ Vt,
                                                     u16* __restrict__ O) {
  __shared__ __align__(16) u16 Ks[2][8 * 1024];   // [buf][chunk c][key 0..31][slot-swz 32 d]
  __shared__ __align__(16) u16 Vs[8 * 1024];      // [d 0..255][slot-swz 32 k]
  int t = threadIdx.x, lane = t & 63, wave = t >> 6;
  int quad = lane >> 4, l16 = lane & 15;
  int h = blockIdx.y, b = blockIdx.z;
  int kvh = h >> 1;

  int swz = ((lane & 3) ^ ((lane >> 2) & 3)) * 8;        // staging-side d/k offset
  int rswz = (quad ^ (l16 & 3)) * 8;                     // read-side slot offset
  const u16* kst = Kb + (size_t)(b * S_ + (lane >> 2)) * QKS_ + kvh * D_ + wave * 64 + swz;
  const u16* vst = Vt + ((size_t)b << 22) + (size_t)(kvh * D_ + wave * 64 + (lane >> 2)) * S_ + swz;

  auto stageK = [&](int kt, int bufi) {
    u16* kdst = &Ks[bufi][wave * 2048];
    const u16* ksrc = kst + (size_t)(kt * 32) * QKS_;
#pragma unroll
    for (int c2 = 0; c2 < 2; c2++)
#pragma unroll
      for (int r = 0; r < 2; r++)
        gll16(ksrc + (size_t)(r * 16) * QKS_ + c2 * 32, kdst + c2 * 1024 + r * 512);
  };  // 4 gll16
  auto stageV = [&](int kt) {
    u16* vdst = &Vs[wave * 2048];
#pragma unroll
    for (int c = 0; c < 4; c++)
      gll16(vst + (size_t)(c * 16) * S_ + kt * 32, vdst + c * 512);
  };  // 4 gll16

#pragma unroll 1
  for (int half = 0; half < 2; half++) {
    // big q-tile first, then the paired small one: iters (64-2bx) + (2bx+2) = 66
    int qb = (half == 0) ? (31 - (int)blockIdx.x) * 64 : (int)blockIdx.x * 64;
    int qw = qb + wave * 16;

    bf16x8 qf[8];
    const u16* qp = Q + ((size_t)(b * S_) + qw + l16) * QKS_ + h * D_;
#pragma unroll
    for (int c = 0; c < 8; c++) qf[c] = *(const bf16x8*)(qp + c * 32 + quad * 8);

    f32x4 o_acc[16] = {};
    float m_s = -3e38f, l_s = 0.f;    // per-lane softmax state for row q = qw + l16

    int nkt = (qb + 64) >> 5;
    stageK(0, 0);
    stageV(0);
#pragma unroll 1
    for (int kt = 0; kt < nkt; kt++) {
      int cur = kt & 1;
      asm volatile("s_waitcnt vmcnt(4)" ::: "memory");
      __builtin_amdgcn_s_barrier();
      asm volatile("" ::: "memory");
      if (kt + 1 < nkt) stageK(kt + 1, cur ^ 1);

      // ---- QK (swapped): sc[key][q], q = l16 ----
      f32x4 sc0 = {}, sc1 = {};
#pragma unroll
      for (int c = 0; c < 8; c++) {
        bf16x8 k0 = *(const bf16x8*)(&Ks[cur][c * 1024 + l16 * 32 + rswz]);
        bf16x8 k1 = *(const bf16x8*)(&Ks[cur][c * 1024 + (l16 + 16) * 32 + rswz]);
        sc0 = __builtin_amdgcn_mfma_f32_16x16x32_bf16(k0, qf[c], sc0, 0, 0, 0);
        sc1 = __builtin_amdgcn_mfma_f32_16x16x32_bf16(k1, qf[c], sc1, 0, 0, 0);
      }

      // ---- lane-local online softmax (row q = qw + l16) ----
      int qg = qw + l16;
      int kbase = kt * 32 + quad * 4;
      float p0[4], p1[4];
      float mx = -1e30f;
#pragma unroll
      for (int r = 0; r < 4; r++) {
        p0[r] = (kbase + r <= qg) ? sc0[r] : -1e30f;
        p1[r] = (kbase + 16 + r <= qg) ? sc1[r] : -1e30f;
        mx = fmaxf(mx, fmaxf(p0[r], p1[r]));
      }
      mx = fmaxf(mx, __shfl_xor(mx, 16));
      mx = fmaxf(mx, __shfl_xor(mx, 32));
      float mn = fmaxf(m_s, mx);
      bool chg = mn > m_s;
      float rsum = 0.f;
#pragma unroll
      for (int r = 0; r < 4; r++) {
        p0[r] = __expf(p0[r] - mn);
        p1[r] = __expf(p1[r] - mn);
        rsum += p0[r] + p1[r];
      }
      if (__any((int)chg)) {
        float alpha = __expf(m_s - mn);
        float ar[4];
#pragma unroll
        for (int r = 0; r < 4; r++) ar[r] = __shfl(alpha, quad * 20 + r);
#pragma unroll
        for (int nt = 0; nt < 16; nt++)
#pragma unroll
          for (int r = 0; r < 4; r++) o_acc[nt][r] *= ar[r];
        l_s *= alpha;
      }
      m_s = mn;
      rsum += __shfl_xor(rsum, 16);
      rsum += __shfl_xor(rsum, 32);
      l_s += rsum;

      // ---- P: C-layout -> A-frag fully in-register (2-stage butterfly) ----
      unsigned int w_[4], x_[4], gl[4], gh[4], sn[4], rc[4];
      w_[0] = (unsigned)f2bf(p0[0]) | ((unsigned)f2bf(p0[1]) << 16);
      w_[1] = (unsigned)f2bf(p0[2]) | ((unsigned)f2bf(p0[3]) << 16);
      w_[2] = (unsigned)f2bf(p1[0]) | ((unsigned)f2bf(p1[1]) << 16);
      w_[3] = (unsigned)f2bf(p1[2]) | ((unsigned)f2bf(p1[3]) << 16);
#pragma unroll
      for (int i = 0; i < 4; i++) x_[i] = (unsigned)__shfl_xor((int)w_[i], 16);
      bool odd = (quad & 1) != 0;
      gl[0] = odd ? x_[0] : w_[0]; gl[1] = odd ? x_[1] : w_[1];
      gl[2] = odd ? w_[0] : x_[0]; gl[3] = odd ? w_[1] : x_[1];
      gh[0] = odd ? x_[2] : w_[2]; gh[1] = odd ? x_[3] : w_[3];
      gh[2] = odd ? w_[2] : x_[2]; gh[3] = odd ? w_[3] : x_[3];
#pragma unroll
      for (int i = 0; i < 4; i++) sn[i] = odd ? gl[i] : gh[i];
#pragma unroll
      for (int i = 0; i < 4; i++) rc[i] = (unsigned)__shfl_xor((int)sn[i], 32);
      union { unsigned int u[4]; bf16x8 v; } pfc;
#pragma unroll
      for (int i = 0; i < 4; i++)
        pfc.u[i] = (quad == 0) ? gl[i] : (quad == 3) ? gh[i] : rc[i];
      bf16x8 pf = pfc.v;

      if (kt + 1 < nkt) asm volatile("s_waitcnt vmcnt(4)" ::: "memory");
      else              asm volatile("s_waitcnt vmcnt(0)" ::: "memory");
      __builtin_amdgcn_s_barrier();
      asm volatile("" ::: "memory");

      // ---- PV ----
#pragma unroll
      for (int nt = 0; nt < 16; nt++) {
        bf16x8 vf = *(const bf16x8*)(&Vs[(nt * 16 + l16) * 32 + rswz]);
        o_acc[nt] = __builtin_amdgcn_mfma_f32_16x16x32_bf16(pf, vf, o_acc[nt], 0, 0, 0);
      }

      asm volatile("s_waitcnt lgkmcnt(0)" ::: "memory");
      __builtin_amdgcn_s_barrier();
      asm volatile("" ::: "memory");
      if (kt + 1 < nkt) stageV(kt + 1);
    }

    float invl = 1.0f / l_s;
    float inv_r[4];
#pragma unroll
    for (int r = 0; r < 4; r++) inv_r[r] = __shfl(invl, quad * 20 + r);
    for (int r = 0; r < 4; r++) {
      int qg2 = qw + quad * 4 + r;
      u16* op = O + ((size_t)(b * S_) + qg2) * HD_ + h * D_;
      for (int nt = 0; nt < 16; nt++) op[nt * 16 + l16] = f2bf(o_acc[nt][r] * inv_r[r]);
    }
  }
}

extern "C" void kernel_launch(void* const* d_in, const int* in_sizes, int n_in,
                              void* d_out, int out_size, void* d_ws, size_t ws_size,
                              hipStream_t stream) {
  const float* hs  = (const float*)d_in[0];
  const float* fc  = (const float*)d_in[1];
  const float* fsn = (const float*)d_in[2];
  // d_in[3] = mask: causal, replicated analytically
  const float* qw  = (const float*)d_in[4];
  const float* kw  = (const float*)d_in[5];
  const float* vw  = (const float*)d_in[6];
  const float* ow  = (const float*)d_in[7];
  const float* qnw = (const float*)d_in[8];
  const float* knw = (const float*)d_in[9];

  char* ws = (char*)d_ws;
  // layout (bytes):
  u16* x_bf   = (u16*)(ws + 0);          // 4096*3072*2 = 25165824 (dead after QKV GEMM)
  u16* vt     = (u16*)(ws + 0);          // 2*2048*2048*2 = 16777216 (overlays dead x_bf)
  u16* wqkv_t = (u16*)(ws + 25165824);   // [8192][3072] = 50331648 (q|k|v transposed, contiguous)
  u16* kw_t   = (u16*)(ws + 50331648);   // = wqkv_t + 4096 rows
  u16* vw_t   = (u16*)(ws + 62914560);   // = wqkv_t + 6144 rows
  u16* ow_t   = (u16*)(ws + 75497472);   // [3072][4096] = 25165824
  u16* xqkv   = (u16*)(ws + 100663296);  // [4096][8192] = 67108864 -> end 167772160
  u16* attn   = (u16*)(ws + 25165824);   // overlays dead wqkv_t after QKV GEMM (33.5MB <= 50.3MB)

  cast_f32_bf16<<<12288, 256, 0, stream>>>(hs, x_bf, 4096 * 3072 / 4);
  transpose_cast<<<dim3(64, 48), 256, 0, stream>>>(qw, wqkv_t, 3072, 4096);
  transpose_cast<<<dim3(32, 48), 256, 0, stream>>>(kw, kw_t, 3072, 2048);
  transpose_cast<<<dim3(32, 48), 256, 0, stream>>>(vw, vw_t, 3072, 2048);
  transpose_cast<<<dim3(48, 64), 256, 0, stream>>>(ow, ow_t, 4096, 3072);

  // merged QKV projection: [4096][3072] x [8192][3072]^T -> [4096][8192]
  gemm256<false><<<dim3(32, 16), 512, 0, stream>>>(x_bf, wqkv_t, xqkv, 4096, 8192, 3072);

  rmsnorm_rope<<<dim3(4096, 4), 256, 0, stream>>>(xqkv, qnw, fc, fsn, 16, QKS_, SCALE_);
  rmsnorm_rope<<<dim3(4096, 2), 256, 0, stream>>>(xqkv + 4096, knw, fc, fsn, 8, QKS_, 1.0f);

  transpose_v<<<dim3(32, 64), 256, 0, stream>>>(xqkv + 6144, vt);

  flash_attn<<<dim3(16, 16, 2), 256, 0, stream>>>(xqkv, xqkv + 4096, vt, attn);

  gemm256<true><<<dim3(12, 16), 512, 0, stream>>>(attn, ow_t, (float*)d_out, 4096, 3072, 4096);
}